// Round 1
// baseline (1097.992 us; speedup 1.0000x reference)
//
#include <hip/hip_runtime.h>
#include <hip/hip_bf16.h>

// ---------------- problem constants ----------------
constexpr int NN = 100000;   // nodes
constexpr int NE = 1600000;  // directed edges
constexpr int NH = 128;      // hidden width (== n_feat)
constexpr int NC = 64;       // classes

// ---------------- workspace layout (bytes) ----------------
constexpr size_t OFF_CNT   = 0;                         // N ints   (counts / chunk-scan in place)
constexpr size_t OFF_RP    = OFF_CNT  + 400384;         // N+1 ints (row_ptr)
constexpr size_t OFF_CUR   = OFF_RP   + 400384;         // N ints   (cursor)
constexpr size_t OFF_BSUM  = OFF_CUR  + 400384;         // 128 ints (block sums for scan)
constexpr size_t OFF_DINV  = OFF_BSUM + 512;            // N floats
constexpr size_t OFF_COL   = OFF_DINV + 400384;         // E ints
constexpr size_t OFF_ECOEF = OFF_COL  + 6400000;        // E floats
constexpr size_t OFF_H     = OFF_ECOEF+ 6400000;        // N*128 floats
constexpr size_t OFF_X     = OFF_H    + 51200000;       // N*128 floats
// total ~116.9 MB

// ---------------- preprocessing kernels ----------------

__global__ __launch_bounds__(256) void count_kernel(const int* __restrict__ dst,
                                                    int* __restrict__ cnt) {
    int e = blockIdx.x * 256 + threadIdx.x;
    if (e < NE) atomicAdd(&cnt[dst[e]], 1);
}

__global__ __launch_bounds__(256) void dinv_kernel(const int* __restrict__ cnt,
                                                   float* __restrict__ dinv) {
    int i = blockIdx.x * 256 + threadIdx.x;
    if (i < NN) dinv[i] = rsqrtf((float)(cnt[i] + 1));   // +1 self loop
}

// exclusive scan, 3 phases, chunk = 1024 (256 thr x 4)
__global__ __launch_bounds__(256) void scan1_kernel(int* __restrict__ data,
                                                    int* __restrict__ bsum) {
    __shared__ int s[256];
    const int t = threadIdx.x;
    const int base = blockIdx.x * 1024;
    int v[4];
    #pragma unroll
    for (int j = 0; j < 4; ++j) {
        int idx = base + t * 4 + j;
        v[j] = (idx < NN) ? data[idx] : 0;
    }
    int tsum = v[0] + v[1] + v[2] + v[3];
    s[t] = tsum;
    __syncthreads();
    for (int off = 1; off < 256; off <<= 1) {
        int add = (t >= off) ? s[t - off] : 0;
        __syncthreads();
        s[t] += add;
        __syncthreads();
    }
    int run = s[t] - tsum;   // exclusive prefix for this thread within chunk
    #pragma unroll
    for (int j = 0; j < 4; ++j) {
        int idx = base + t * 4 + j;
        if (idx < NN) data[idx] = run;
        run += v[j];
    }
    if (t == 255) bsum[blockIdx.x] = s[255];
}

__global__ __launch_bounds__(128) void scan2_kernel(int* __restrict__ bsum, int nb) {
    __shared__ int s[128];
    const int t = threadIdx.x;
    int v = (t < nb) ? bsum[t] : 0;
    s[t] = v;
    __syncthreads();
    for (int off = 1; off < 128; off <<= 1) {
        int add = (t >= off) ? s[t - off] : 0;
        __syncthreads();
        s[t] += add;
        __syncthreads();
    }
    if (t < nb) bsum[t] = s[t] - v;  // exclusive
}

__global__ __launch_bounds__(256) void scan3_kernel(const int* __restrict__ chunkExcl,
                                                    const int* __restrict__ boff,
                                                    int* __restrict__ row_ptr,
                                                    int* __restrict__ cursor) {
    int i = blockIdx.x * 256 + threadIdx.x;
    if (i < NN) {
        int v = chunkExcl[i] + boff[i >> 10];
        row_ptr[i] = v;
        cursor[i]  = v;
    }
    if (i == 0) row_ptr[NN] = NE;
}

__global__ __launch_bounds__(256) void fill_kernel(const int* __restrict__ src,
                                                   const int* __restrict__ dst,
                                                   const float* __restrict__ dinv,
                                                   int* __restrict__ cursor,
                                                   int* __restrict__ col,
                                                   float* __restrict__ ecoef) {
    int e = blockIdx.x * 256 + threadIdx.x;
    if (e >= NE) return;
    int s = src[e], d = dst[e];
    int pos = atomicAdd(&cursor[d], 1);
    col[pos]   = s;
    ecoef[pos] = dinv[s] * dinv[d];
}

// ---------------- GEMM:  H[n][houtoff + 64 cols] = X[n][:] @ W ----------------
// blockIdx.y selects which 64-col half (W0 or W1).  Register tile: 4 nodes x 4 outs.
__global__ __launch_bounds__(256) void gemm_kernel(const float* __restrict__ X,
                                                   const float* __restrict__ W0,
                                                   const float* __restrict__ W1,
                                                   int wstride,
                                                   float* __restrict__ H) {
    __shared__ float sW[128][64];
    __shared__ float sX[64][132];   // padded: 132 % 32 == 4 -> 2-way (free) on reads

    const int t = threadIdx.x;
    const int h = blockIdx.y;
    const float* __restrict__ W = h ? W1 : W0;

    // load W slice: 128 x 64
    #pragma unroll
    for (int i = 0; i < 8; ++i) {
        int e = t * 4 + i * 1024;
        int k = e >> 6, c = e & 63;
        float4 w = *(const float4*)&W[(size_t)k * wstride + c];
        *(float4*)&sW[k][c] = w;
    }
    // load X tile: 64 nodes x 128
    const int tileBase = blockIdx.x * 64;
    #pragma unroll
    for (int i = 0; i < 8; ++i) {
        int e = t * 4 + i * 1024;
        int node = e >> 7, k = e & 127;
        int gn = tileBase + node;
        float4 v = make_float4(0.f, 0.f, 0.f, 0.f);
        if (gn < NN) v = *(const float4*)&X[(size_t)gn * 128 + k];
        *(float4*)&sX[node][k] = v;
    }
    __syncthreads();

    const int tx = t & 15;    // out group: cols tx*4 .. tx*4+3
    const int ty = t >> 4;    // node group: nodes ty*4 .. ty*4+3

    float acc[4][4];
    #pragma unroll
    for (int r = 0; r < 4; ++r)
        #pragma unroll
        for (int c = 0; c < 4; ++c) acc[r][c] = 0.f;

    #pragma unroll 4
    for (int k = 0; k < 128; k += 4) {
        float4 xr[4], wr[4];
        #pragma unroll
        for (int r = 0; r < 4; ++r) xr[r] = *(const float4*)&sX[ty * 4 + r][k];
        #pragma unroll
        for (int j = 0; j < 4; ++j) wr[j] = *(const float4*)&sW[k + j][tx * 4];
        #pragma unroll
        for (int r = 0; r < 4; ++r) {
            #pragma unroll
            for (int j = 0; j < 4; ++j) {
                float xv = (j == 0) ? xr[r].x : (j == 1) ? xr[r].y : (j == 2) ? xr[r].z : xr[r].w;
                acc[r][0] += xv * wr[j].x;
                acc[r][1] += xv * wr[j].y;
                acc[r][2] += xv * wr[j].z;
                acc[r][3] += xv * wr[j].w;
            }
        }
    }

    #pragma unroll
    for (int r = 0; r < 4; ++r) {
        int gn = tileBase + ty * 4 + r;
        if (gn < NN) {
            float4 o = make_float4(acc[r][0], acc[r][1], acc[r][2], acc[r][3]);
            *(float4*)&H[(size_t)gn * 128 + h * 64 + tx * 4] = o;
        }
    }
}

// ---------------- aggregation: 128-feature layers (conv + bias + residual + relu) ----------------
__global__ __launch_bounds__(256) void agg128_kernel(const float* __restrict__ H,
                                                     const float* __restrict__ Xold,
                                                     const int* __restrict__ rp,
                                                     const int* __restrict__ col,
                                                     const float* __restrict__ ecoef,
                                                     const float* __restrict__ dinv,
                                                     const float* __restrict__ bias,
                                                     float* __restrict__ Xnew) {
    const int wid  = threadIdx.x >> 6;
    const int lane = threadIdx.x & 63;
    const int i = blockIdx.x * 4 + wid;
    if (i >= NN) return;

    const float2* __restrict__ H2 = (const float2*)H;
    const float di = dinv[i];
    const float sc = di * di;

    float2 hv = H2[(size_t)i * 64 + lane];
    float ax = hv.x * sc, ay = hv.y * sc;

    const int beg = rp[i], end = rp[i + 1];
    for (int e = beg; e < end; ++e) {
        int s   = col[e];
        float c = ecoef[e];
        float2 m = H2[(size_t)s * 64 + lane];
        ax += c * m.x;
        ay += c * m.y;
    }

    float2 b2 = ((const float2*)bias)[lane];
    float2 xo = ((const float2*)Xold)[(size_t)i * 64 + lane];
    float ox = fmaxf(ax + b2.x + xo.x, 0.f);
    float oy = fmaxf(ay + b2.y + xo.y, 0.f);
    ((float2*)Xnew)[(size_t)i * 64 + lane] = make_float2(ox, oy);
}

// ---------------- final layer: 64-feature conv + bias + skip ----------------
// H rows: cols 0..63 = x@W_out, cols 64..127 = x@W_skip_out
__global__ __launch_bounds__(256) void aggout_kernel(const float* __restrict__ H,
                                                     const int* __restrict__ rp,
                                                     const int* __restrict__ col,
                                                     const float* __restrict__ ecoef,
                                                     const float* __restrict__ dinv,
                                                     const float* __restrict__ bias,
                                                     float* __restrict__ out) {
    const int wid  = threadIdx.x >> 6;
    const int lane = threadIdx.x & 63;
    const int i = blockIdx.x * 4 + wid;
    if (i >= NN) return;
    if (lane >= 32) return;   // 64 features = 32 lanes x float2

    const float2* __restrict__ H2 = (const float2*)H;
    const float di = dinv[i];
    const float sc = di * di;

    float2 hv = H2[(size_t)i * 64 + lane];
    float ax = hv.x * sc, ay = hv.y * sc;

    const int beg = rp[i], end = rp[i + 1];
    for (int e = beg; e < end; ++e) {
        int s   = col[e];
        float c = ecoef[e];
        float2 m = H2[(size_t)s * 64 + lane];
        ax += c * m.x;
        ay += c * m.y;
    }

    float2 b2 = ((const float2*)bias)[lane];
    float2 sk = H2[(size_t)i * 64 + 32 + lane];   // skip part of the row
    ((float2*)out)[(size_t)i * 32 + lane] = make_float2(ax + b2.x + sk.x, ay + b2.y + sk.y);
}

// ---------------- launch ----------------
extern "C" void kernel_launch(void* const* d_in, const int* in_sizes, int n_in,
                              void* d_out, int out_size, void* d_ws, size_t ws_size,
                              hipStream_t stream) {
    const float* x      = (const float*)d_in[0];
    const int*   ei     = (const int*)d_in[1];
    const float* W_in   = (const float*)d_in[2];
    const float* b_in   = (const float*)d_in[3];
    const float* W_mid0 = (const float*)d_in[4];
    const float* b_mid0 = (const float*)d_in[5];
    const float* W_mid1 = (const float*)d_in[6];
    const float* b_mid1 = (const float*)d_in[7];
    const float* W_out  = (const float*)d_in[8];
    const float* b_out  = (const float*)d_in[9];
    const float* W_skip = (const float*)d_in[10];

    const int* esrc = ei;        // edge_index[0]
    const int* edst = ei + NE;   // edge_index[1]

    char* ws = (char*)d_ws;
    int*   cnt    = (int*)  (ws + OFF_CNT);
    int*   rp     = (int*)  (ws + OFF_RP);
    int*   cur    = (int*)  (ws + OFF_CUR);
    int*   bsum   = (int*)  (ws + OFF_BSUM);
    float* dinv   = (float*)(ws + OFF_DINV);
    int*   col    = (int*)  (ws + OFF_COL);
    float* ecoef  = (float*)(ws + OFF_ECOEF);
    float* hbuf   = (float*)(ws + OFF_H);
    float* xbuf   = (float*)(ws + OFF_X);
    float* outp   = (float*)d_out;

    const int nbScan = (NN + 1023) / 1024;           // 98
    const dim3 gemmGrid((NN + 63) / 64, 2);          // 1563 x 2
    const int aggGrid = (NN + 3) / 4;                // 25000
    const int eGrid   = (NE + 255) / 256;            // 6250
    const int nGrid   = (NN + 255) / 256;            // 391

    // ---- graph preprocessing (every call: ws is not re-initialized by harness) ----
    hipMemsetAsync(cnt, 0, (size_t)NN * 4, stream);
    count_kernel<<<eGrid, 256, 0, stream>>>(edst, cnt);
    dinv_kernel<<<nGrid, 256, 0, stream>>>(cnt, dinv);
    scan1_kernel<<<nbScan, 256, 0, stream>>>(cnt, bsum);
    scan2_kernel<<<1, 128, 0, stream>>>(bsum, nbScan);
    scan3_kernel<<<nGrid, 256, 0, stream>>>(cnt, bsum, rp, cur);
    fill_kernel<<<eGrid, 256, 0, stream>>>(esrc, edst, dinv, cur, col, ecoef);

    // ---- layer 1 (reads input x, writes xbuf) ----
    gemm_kernel<<<gemmGrid, 256, 0, stream>>>(x, W_in, W_in + 64, 128, hbuf);
    agg128_kernel<<<aggGrid, 256, 0, stream>>>(hbuf, x, rp, col, ecoef, dinv, b_in, xbuf);

    // ---- layer 2 ----
    gemm_kernel<<<gemmGrid, 256, 0, stream>>>(xbuf, W_mid0, W_mid0 + 64, 128, hbuf);
    agg128_kernel<<<aggGrid, 256, 0, stream>>>(hbuf, xbuf, rp, col, ecoef, dinv, b_mid0, xbuf);

    // ---- layer 3 ----
    gemm_kernel<<<gemmGrid, 256, 0, stream>>>(xbuf, W_mid1, W_mid1 + 64, 128, hbuf);
    agg128_kernel<<<aggGrid, 256, 0, stream>>>(hbuf, xbuf, rp, col, ecoef, dinv, b_mid1, xbuf);

    // ---- layer 4: fused [W_out | W_skip_out] GEMM, then conv+bias+skip ----
    gemm_kernel<<<gemmGrid, 256, 0, stream>>>(xbuf, W_out, W_skip, 64, hbuf);
    aggout_kernel<<<aggGrid, 256, 0, stream>>>(hbuf, rp, col, ecoef, dinv, b_out, outp);
}

// Round 2
// 899.067 us; speedup vs baseline: 1.2213x; 1.2213x over previous
//
#include <hip/hip_runtime.h>
#include <hip/hip_bf16.h>

// ---------------- problem constants ----------------
constexpr int NN = 100000;   // nodes
constexpr int NE = 1600000;  // directed edges
constexpr int NH = 128;      // hidden width (== n_feat)
constexpr int NC = 64;       // classes

// ---------------- workspace layout (bytes) ----------------
constexpr size_t OFF_CNT   = 0;                         // N ints   (counts / chunk-scan in place)
constexpr size_t OFF_RP    = OFF_CNT  + 400384;         // N+1 ints (row_ptr)
constexpr size_t OFF_CUR   = OFF_RP   + 400384;         // N ints   (cursor)
constexpr size_t OFF_BSUM  = OFF_CUR  + 400384;         // 128 ints (block sums for scan)
constexpr size_t OFF_DINV  = OFF_BSUM + 512;            // N floats
constexpr size_t OFF_COL   = OFF_DINV + 400384;         // E ints
constexpr size_t OFF_H     = OFF_COL  + 6400000;        // N*128 floats (prescaled by dinv per half, see scaleMask)
constexpr size_t OFF_X     = OFF_H    + 51200000;       // N*128 floats
// total ~110 MB

// ---------------- preprocessing kernels ----------------

__global__ __launch_bounds__(256) void count_kernel(const int* __restrict__ dst,
                                                    int* __restrict__ cnt) {
    int e = blockIdx.x * 256 + threadIdx.x;
    if (e < NE) atomicAdd(&cnt[dst[e]], 1);
}

__global__ __launch_bounds__(256) void dinv_kernel(const int* __restrict__ cnt,
                                                   float* __restrict__ dinv) {
    int i = blockIdx.x * 256 + threadIdx.x;
    if (i < NN) dinv[i] = rsqrtf((float)(cnt[i] + 1));   // +1 self loop
}

// exclusive scan, 3 phases, chunk = 1024 (256 thr x 4)
__global__ __launch_bounds__(256) void scan1_kernel(int* __restrict__ data,
                                                    int* __restrict__ bsum) {
    __shared__ int s[256];
    const int t = threadIdx.x;
    const int base = blockIdx.x * 1024;
    int v[4];
    #pragma unroll
    for (int j = 0; j < 4; ++j) {
        int idx = base + t * 4 + j;
        v[j] = (idx < NN) ? data[idx] : 0;
    }
    int tsum = v[0] + v[1] + v[2] + v[3];
    s[t] = tsum;
    __syncthreads();
    for (int off = 1; off < 256; off <<= 1) {
        int add = (t >= off) ? s[t - off] : 0;
        __syncthreads();
        s[t] += add;
        __syncthreads();
    }
    int run = s[t] - tsum;   // exclusive prefix for this thread within chunk
    #pragma unroll
    for (int j = 0; j < 4; ++j) {
        int idx = base + t * 4 + j;
        if (idx < NN) data[idx] = run;
        run += v[j];
    }
    if (t == 255) bsum[blockIdx.x] = s[255];
}

__global__ __launch_bounds__(128) void scan2_kernel(int* __restrict__ bsum, int nb) {
    __shared__ int s[128];
    const int t = threadIdx.x;
    int v = (t < nb) ? bsum[t] : 0;
    s[t] = v;
    __syncthreads();
    for (int off = 1; off < 128; off <<= 1) {
        int add = (t >= off) ? s[t - off] : 0;
        __syncthreads();
        s[t] += add;
        __syncthreads();
    }
    if (t < nb) bsum[t] = s[t] - v;  // exclusive
}

__global__ __launch_bounds__(256) void scan3_kernel(const int* __restrict__ chunkExcl,
                                                    const int* __restrict__ boff,
                                                    int* __restrict__ row_ptr,
                                                    int* __restrict__ cursor) {
    int i = blockIdx.x * 256 + threadIdx.x;
    if (i < NN) {
        int v = chunkExcl[i] + boff[i >> 10];
        row_ptr[i] = v;
        cursor[i]  = v;
    }
    if (i == 0) row_ptr[NN] = NE;
}

__global__ __launch_bounds__(256) void fill_kernel(const int* __restrict__ src,
                                                   const int* __restrict__ dst,
                                                   int* __restrict__ cursor,
                                                   int* __restrict__ col) {
    int e = blockIdx.x * 256 + threadIdx.x;
    if (e >= NE) return;
    int s = src[e], d = dst[e];
    int pos = atomicAdd(&cursor[d], 1);
    col[pos] = s;
}

// ---------------- GEMM:  H[n][h*64 + 64 cols] = X[n][:] @ W, optionally row-prescaled by dinv ----
// blockIdx.y selects which 64-col half (W0 or W1).  Register tile: 4 nodes x 4 outs.
// scaleMask bit h: multiply that half's output row by dinv[row] (pre-scales messages so the
// aggregation inner loop is a pure sum: coef = dinv[s]*dinv[d] factors).
__global__ __launch_bounds__(256) void gemm_kernel(const float* __restrict__ X,
                                                   const float* __restrict__ W0,
                                                   const float* __restrict__ W1,
                                                   int wstride,
                                                   const float* __restrict__ dinv,
                                                   int scaleMask,
                                                   float* __restrict__ H) {
    __shared__ float sW[128][64];
    __shared__ float sX[64][132];   // padded: 132 % 32 == 4 -> 2-way (free) on reads

    const int t = threadIdx.x;
    const int h = blockIdx.y;
    const float* __restrict__ W = h ? W1 : W0;
    const bool doScale = (scaleMask >> h) & 1;

    // load W slice: 128 x 64
    #pragma unroll
    for (int i = 0; i < 8; ++i) {
        int e = t * 4 + i * 1024;
        int k = e >> 6, c = e & 63;
        float4 w = *(const float4*)&W[(size_t)k * wstride + c];
        *(float4*)&sW[k][c] = w;
    }
    // load X tile: 64 nodes x 128
    const int tileBase = blockIdx.x * 64;
    #pragma unroll
    for (int i = 0; i < 8; ++i) {
        int e = t * 4 + i * 1024;
        int node = e >> 7, k = e & 127;
        int gn = tileBase + node;
        float4 v = make_float4(0.f, 0.f, 0.f, 0.f);
        if (gn < NN) v = *(const float4*)&X[(size_t)gn * 128 + k];
        *(float4*)&sX[node][k] = v;
    }
    __syncthreads();

    const int tx = t & 15;    // out group: cols tx*4 .. tx*4+3
    const int ty = t >> 4;    // node group: nodes ty*4 .. ty*4+3

    float acc[4][4];
    #pragma unroll
    for (int r = 0; r < 4; ++r)
        #pragma unroll
        for (int c = 0; c < 4; ++c) acc[r][c] = 0.f;

    #pragma unroll 4
    for (int k = 0; k < 128; k += 4) {
        float4 xr[4], wr[4];
        #pragma unroll
        for (int r = 0; r < 4; ++r) xr[r] = *(const float4*)&sX[ty * 4 + r][k];
        #pragma unroll
        for (int j = 0; j < 4; ++j) wr[j] = *(const float4*)&sW[k + j][tx * 4];
        #pragma unroll
        for (int r = 0; r < 4; ++r) {
            #pragma unroll
            for (int j = 0; j < 4; ++j) {
                float xv = (j == 0) ? xr[r].x : (j == 1) ? xr[r].y : (j == 2) ? xr[r].z : xr[r].w;
                acc[r][0] += xv * wr[j].x;
                acc[r][1] += xv * wr[j].y;
                acc[r][2] += xv * wr[j].z;
                acc[r][3] += xv * wr[j].w;
            }
        }
    }

    #pragma unroll
    for (int r = 0; r < 4; ++r) {
        int gn = tileBase + ty * 4 + r;
        if (gn < NN) {
            float s = doScale ? dinv[gn] : 1.f;
            float4 o = make_float4(acc[r][0] * s, acc[r][1] * s, acc[r][2] * s, acc[r][3] * s);
            *(float4*)&H[(size_t)gn * 128 + h * 64 + tx * 4] = o;
        }
    }
}

// ---------------- aggregation: 128-feature layers (conv + bias + residual + relu) ----------------
// Hs rows are prescaled by dinv[row]; out = relu(dinv[i]*(Hs[i] + sum_e Hs[col[e]]) + bias + Xold)
__global__ __launch_bounds__(256) void agg128_kernel(const float* __restrict__ Hs,
                                                     const float* __restrict__ Xold,
                                                     const int* __restrict__ rp,
                                                     const int* __restrict__ col,
                                                     const float* __restrict__ dinv,
                                                     const float* __restrict__ bias,
                                                     float* __restrict__ Xnew) {
    const int wid  = threadIdx.x >> 6;
    const int lane = threadIdx.x & 63;
    const int i = blockIdx.x * 4 + wid;
    if (i >= NN) return;

    const float2* __restrict__ H2 = (const float2*)Hs;

    // issue long-latency per-node loads early; results consumed at the end
    const float di = dinv[i];
    const float2 b2 = ((const float2*)bias)[lane];
    const float2 xo = ((const float2*)Xold)[(size_t)i * 64 + lane];

    float2 hv = H2[(size_t)i * 64 + lane];   // self term (coef dinv[i]^2 = di * prescale)
    float ax = hv.x, ay = hv.y;

    const int beg = rp[i], end = rp[i + 1];
    int e = beg;
    // 4x unrolled gather: 4 independent 512B row reads in flight per wave
    for (; e + 4 <= end; e += 4) {
        int s0 = col[e], s1 = col[e + 1], s2 = col[e + 2], s3 = col[e + 3];
        float2 m0 = H2[(size_t)s0 * 64 + lane];
        float2 m1 = H2[(size_t)s1 * 64 + lane];
        float2 m2 = H2[(size_t)s2 * 64 + lane];
        float2 m3 = H2[(size_t)s3 * 64 + lane];
        ax += (m0.x + m1.x) + (m2.x + m3.x);
        ay += (m0.y + m1.y) + (m2.y + m3.y);
    }
    for (; e < end; ++e) {
        float2 m = H2[(size_t)col[e] * 64 + lane];
        ax += m.x;
        ay += m.y;
    }

    float ox = fmaxf(di * ax + b2.x + xo.x, 0.f);
    float oy = fmaxf(di * ay + b2.y + xo.y, 0.f);
    ((float2*)Xnew)[(size_t)i * 64 + lane] = make_float2(ox, oy);
}

// ---------------- final layer: 64-feature conv + bias + skip ----------------
// H rows: cols 0..63 = x@W_out (prescaled by dinv), cols 64..127 = x@W_skip_out (raw)
// one float per lane -> all 64 lanes active
__global__ __launch_bounds__(256) void aggout_kernel(const float* __restrict__ Hs,
                                                     const int* __restrict__ rp,
                                                     const int* __restrict__ col,
                                                     const float* __restrict__ dinv,
                                                     const float* __restrict__ bias,
                                                     float* __restrict__ out) {
    const int wid  = threadIdx.x >> 6;
    const int lane = threadIdx.x & 63;
    const int i = blockIdx.x * 4 + wid;
    if (i >= NN) return;

    const float di = dinv[i];
    const float b  = bias[lane];
    const float sk = Hs[(size_t)i * 128 + 64 + lane];   // skip projection (unscaled)

    float a = Hs[(size_t)i * 128 + lane];               // self term
    const int beg = rp[i], end = rp[i + 1];
    int e = beg;
    for (; e + 4 <= end; e += 4) {
        int s0 = col[e], s1 = col[e + 1], s2 = col[e + 2], s3 = col[e + 3];
        float m0 = Hs[(size_t)s0 * 128 + lane];
        float m1 = Hs[(size_t)s1 * 128 + lane];
        float m2 = Hs[(size_t)s2 * 128 + lane];
        float m3 = Hs[(size_t)s3 * 128 + lane];
        a += (m0 + m1) + (m2 + m3);
    }
    for (; e < end; ++e) a += Hs[(size_t)col[e] * 128 + lane];

    out[(size_t)i * 64 + lane] = di * a + b + sk;
}

// ---------------- launch ----------------
extern "C" void kernel_launch(void* const* d_in, const int* in_sizes, int n_in,
                              void* d_out, int out_size, void* d_ws, size_t ws_size,
                              hipStream_t stream) {
    const float* x      = (const float*)d_in[0];
    const int*   ei     = (const int*)d_in[1];
    const float* W_in   = (const float*)d_in[2];
    const float* b_in   = (const float*)d_in[3];
    const float* W_mid0 = (const float*)d_in[4];
    const float* b_mid0 = (const float*)d_in[5];
    const float* W_mid1 = (const float*)d_in[6];
    const float* b_mid1 = (const float*)d_in[7];
    const float* W_out  = (const float*)d_in[8];
    const float* b_out  = (const float*)d_in[9];
    const float* W_skip = (const float*)d_in[10];

    const int* esrc = ei;        // edge_index[0]
    const int* edst = ei + NE;   // edge_index[1]

    char* ws = (char*)d_ws;
    int*   cnt    = (int*)  (ws + OFF_CNT);
    int*   rp     = (int*)  (ws + OFF_RP);
    int*   cur    = (int*)  (ws + OFF_CUR);
    int*   bsum   = (int*)  (ws + OFF_BSUM);
    float* dinv   = (float*)(ws + OFF_DINV);
    int*   col    = (int*)  (ws + OFF_COL);
    float* hbuf   = (float*)(ws + OFF_H);
    float* xbuf   = (float*)(ws + OFF_X);
    float* outp   = (float*)d_out;

    const int nbScan = (NN + 1023) / 1024;           // 98
    const dim3 gemmGrid((NN + 63) / 64, 2);          // 1563 x 2
    const int aggGrid = (NN + 3) / 4;                // 25000
    const int eGrid   = (NE + 255) / 256;            // 6250
    const int nGrid   = (NN + 255) / 256;            // 391

    // ---- graph preprocessing (every call: ws is not re-initialized by harness) ----
    hipMemsetAsync(cnt, 0, (size_t)NN * 4, stream);
    count_kernel<<<eGrid, 256, 0, stream>>>(edst, cnt);
    dinv_kernel<<<nGrid, 256, 0, stream>>>(cnt, dinv);
    scan1_kernel<<<nbScan, 256, 0, stream>>>(cnt, bsum);
    scan2_kernel<<<1, 128, 0, stream>>>(bsum, nbScan);
    scan3_kernel<<<nGrid, 256, 0, stream>>>(cnt, bsum, rp, cur);
    fill_kernel<<<eGrid, 256, 0, stream>>>(esrc, edst, cur, col);

    // ---- layer 1 (reads input x, writes xbuf) ----
    gemm_kernel<<<gemmGrid, 256, 0, stream>>>(x, W_in, W_in + 64, 128, dinv, 3, hbuf);
    agg128_kernel<<<aggGrid, 256, 0, stream>>>(hbuf, x, rp, col, dinv, b_in, xbuf);

    // ---- layer 2 ----
    gemm_kernel<<<gemmGrid, 256, 0, stream>>>(xbuf, W_mid0, W_mid0 + 64, 128, dinv, 3, hbuf);
    agg128_kernel<<<aggGrid, 256, 0, stream>>>(hbuf, xbuf, rp, col, dinv, b_mid0, xbuf);

    // ---- layer 3 ----
    gemm_kernel<<<gemmGrid, 256, 0, stream>>>(xbuf, W_mid1, W_mid1 + 64, 128, dinv, 3, hbuf);
    agg128_kernel<<<aggGrid, 256, 0, stream>>>(hbuf, xbuf, rp, col, dinv, b_mid1, xbuf);

    // ---- layer 4: fused [W_out | W_skip_out] GEMM (scale only W_out half), then conv+bias+skip ----
    gemm_kernel<<<gemmGrid, 256, 0, stream>>>(xbuf, W_out, W_skip, 64, dinv, 1, hbuf);
    aggout_kernel<<<aggGrid, 256, 0, stream>>>(hbuf, rp, col, dinv, b_out, outp);
}